// Round 6
// baseline (220.023 us; speedup 1.0000x reference)
//
#include <hip/hip_runtime.h>

// SimVQuantizer: B=8, D=128 (N_CB=8 x CDIM=16), H=W=32 -> 8192 pixels.
// Outputs (FLOAT32, concatenated flat):
//   quantized  [8,128,32,32]  = 1048576   @ 0
//   indices    [8,8,32,32]    =   65536   @ 1048576
//   commitment scalar         =       1   @ 1114112
//   new_codebooks [8,1024,16] =  131072   @ 1114113
//   new_count  [8,1024]       =    8192   @ 1245185
//   new_weight [8,1024,16]    =  131072   @ 1253377

#define NCB   8
#define VOCAB 1024
#define CDIM  16
#define NPIX  8192   // B*H*W
#define HW    1024   // H*W

#define OFF_QUANT  0
#define OFF_IDX    1048576
#define OFF_COMMIT 1114112
#define OFF_NCB    1114113
#define OFF_NCNT   1245185
#define OFF_NWT    1253377

// workspace layout (floats): counts[8*1024], sums[8*1024*16], then a double
#define WS_COUNTS_OFF 0
#define WS_SUMS_OFF   (NCB * VOCAB)
#define WS_COMMIT_BYTE_OFF (size_t)((NCB * VOCAB) * 4 + (NCB * VOCAB * CDIM) * 4) // 557056
#define WS_ZERO_BYTES (WS_COMMIT_BYTE_OFF + 8)

typedef float v2f __attribute__((ext_vector_type(2)));

// numpy pairwise_sum (order-preserving 8-accumulator) for n=16:
// r[j] = a[j] + a[j+8];  res = ((r0+r1)+(r2+r3)) + ((r4+r5)+(r6+r7))
__device__ __forceinline__ float npsum16(const float m[16]) {
#pragma clang fp contract(off)
  float r0 = m[0] + m[8];
  float r1 = m[1] + m[9];
  float r2 = m[2] + m[10];
  float r3 = m[3] + m[11];
  float r4 = m[4] + m[12];
  float r5 = m[5] + m[13];
  float r6 = m[6] + m[14];
  float r7 = m[7] + m[15];
  return ((r0 + r1) + (r2 + r3)) + ((r4 + r5) + (r6 + r7));
}

__device__ __forceinline__ float npsum16sq(const float a[16]) {
#pragma clang fp contract(off)
  float m[16];
#pragma unroll
  for (int d = 0; d < 16; ++d) m[d] = a[d] * a[d];
  return npsum16(m);
}

// 256 blocks x 512 threads. Block = (codebook c = bx>>5, pixel-group g = bx&31)
// covering 256 pixels. Lane owns 4 pixels (sub 0..3: pixel g*256+sub*64+lane).
// Wave w scans 128 vocab entries (64 per LDS phase) for all 256 pixels ->
// each 64B entry-fetch feeds 256 distances (4x better LDS-pipe amortization).
__global__ __launch_bounds__(512, 2) void k_assign(
    const float* __restrict__ z, const float* __restrict__ cb,
    float* __restrict__ out, float* __restrict__ ws_counts,
    float* __restrict__ ws_sums, double* __restrict__ ws_commit) {
  __shared__ float4 s_cb4[512 * 4];  // 32KB: current phase's 512 entries
  __shared__ float s_c2[VOCAB];      // 4KB
  __shared__ float s_best[8 * 256];  // 8KB
  __shared__ int s_bi[8 * 256];      // 8KB

  const int c = blockIdx.x >> 5;
  const int g = blockIdx.x & 31;
  const int t = threadIdx.x;
  const int lane = t & 63;
  const int w = t >> 6;

  const float* cbc = cb + (size_t)c * VOCAB * CDIM;
  const float4* cb4 = reinterpret_cast<const float4*>(cbc);

  // ||cb||^2 for all 1024 entries (np.sum(cb*cb,-1), pairwise 8-acc order)
  for (int v = t; v < VOCAB; v += 512) {
    float e[16];
#pragma unroll
    for (int d = 0; d < 16; ++d) e[d] = cbc[(size_t)v * CDIM + d];
    s_c2[v] = npsum16sq(e);
  }

  // load z for this wave's 4 pixel-subs (every wave holds all 256 pixels;
  // block footprint 16KB -> L1-resident after first wave)
  v2f Z[4][8];
  float z2[4];
#pragma unroll
  for (int sub = 0; sub < 4; ++sub) {
    const int n = g * 256 + sub * 64 + lane;
    const int b = n >> 10;
    const int hw = n & 1023;
    const float* zbase = z + ((size_t)(b * 128 + c * 16)) * HW + hw;
    float zv[16];
#pragma unroll
    for (int d = 0; d < 16; ++d) zv[d] = zbase[(size_t)d * HW];
    z2[sub] = npsum16sq(zv);
#pragma unroll
    for (int j = 0; j < 8; ++j) Z[sub][j] = (v2f){zv[2 * j], zv[2 * j + 1]};
  }

  float best[4] = {INFINITY, INFINITY, INFINITY, INFINITY};
  int bi[4] = {0, 0, 0, 0};

  for (int p = 0; p < 2; ++p) {
    __syncthreads();  // p=0: c2 done; p=1: all readers done with s_cb4
    // stage 512 entries (32KB): 4 float4 per thread, coalesced
#pragma unroll
    for (int k = 0; k < 4; ++k)
      s_cb4[k * 512 + t] = cb4[p * 2048 + k * 512 + t];
    __syncthreads();

    const float4* sl4 = s_cb4 + w * 256;  // wave's 64 entries (wave-uniform)
    const int vbase = p * 512 + w * 64;
#pragma unroll 2
    for (int vo = 0; vo < 64; ++vo) {
      const float4 q0 = sl4[vo * 4 + 0];
      const float4 q1 = sl4[vo * 4 + 1];
      const float4 q2 = sl4[vo * 4 + 2];
      const float4 q3 = sl4[vo * 4 + 3];
      const float cc2 = s_c2[vbase + vo];
      const int v = vbase + vo;
#pragma unroll
      for (int sub = 0; sub < 4; ++sub) {
        float d2;
        {
#pragma clang fp contract(off)
          // exact numpy-einsum order via packed fp32 (bit-identical/elem):
          // l_j = (m_j+m_{j+4}) + (m_{j+8}+m_{j+12}); res = (l0+l1)+(l2+l3)
          const v2f M0 = Z[sub][0] * (v2f){q0.x, q0.y};
          const v2f M1 = Z[sub][1] * (v2f){q0.z, q0.w};
          const v2f M2 = Z[sub][2] * (v2f){q1.x, q1.y};
          const v2f M3 = Z[sub][3] * (v2f){q1.z, q1.w};
          const v2f M4 = Z[sub][4] * (v2f){q2.x, q2.y};
          const v2f M5 = Z[sub][5] * (v2f){q2.z, q2.w};
          const v2f M6 = Z[sub][6] * (v2f){q3.x, q3.y};
          const v2f M7 = Z[sub][7] * (v2f){q3.z, q3.w};
          const v2f A = M0 + M2;
          const v2f Bp = M1 + M3;
          const v2f C = M4 + M6;
          const v2f D = M5 + M7;
          const v2f E = A + C;   // (l0, l1)
          const v2f F = Bp + D;  // (l2, l3)
          const float dot = (E.x + E.y) + (F.x + F.y);
          d2 = (z2[sub] - 2.0f * dot) + cc2;  // np: (z2-2*einsum)+c2
        }
        const bool lt = d2 < best[sub];  // strict <, ascending v within wave
        best[sub] = lt ? d2 : best[sub];
        bi[sub] = lt ? v : bi[sub];
      }
    }
  }
#pragma unroll
  for (int sub = 0; sub < 4; ++sub) {
    s_best[w * 256 + sub * 64 + lane] = best[sub];
    s_bi[w * 256 + sub * 64 + lane] = bi[sub];
  }
  __syncthreads();

  // waves 0..3: wave w finalizes sub w (it holds that sub's z in registers).
  // Combine the 8 per-wave candidates with index tie-break -> np first-wins.
  if (w < 4) {
    const int sub = w;
    float bb = s_best[sub * 64 + lane];
    int ii = s_bi[sub * 64 + lane];
#pragma unroll
    for (int s = 1; s < 8; ++s) {
      const float ob = s_best[s * 256 + sub * 64 + lane];
      const int oi = s_bi[s * 256 + sub * 64 + lane];
      const bool take = (ob < bb) || (ob == bb && oi < ii);
      bb = take ? ob : bb;
      ii = take ? oi : ii;
    }

    const int n = g * 256 + sub * 64 + lane;
    const int b = n >> 10;
    const int hw = n & 1023;
    float zv[16];
#pragma unroll
    for (int j = 0; j < 8; ++j) {
      zv[2 * j] = Z[sub][j].x;
      zv[2 * j + 1] = Z[sub][j].y;
    }

    // gather winning entry (L2-hot), write outputs
    const float* qe = cbc + (size_t)ii * CDIM;
    float comm = 0.f;
#pragma unroll
    for (int d = 0; d < 16; ++d) {
      float zq = qe[d];
      float diff, qst;
      {
#pragma clang fp contract(off)
        diff = zv[d] - zq;
        qst = zv[d] + (zq - zv[d]);  // zq_st = zp + (zq - zp), as np computes
      }
      comm += diff * diff;
      out[OFF_QUANT + ((size_t)(b * 128 + c * 16 + d)) * HW + hw] = qst;
    }
    out[OFF_IDX + ((size_t)(b * NCB + c)) * HW + hw] = (float)ii;

    atomicAdd(&ws_counts[c * VOCAB + ii], 1.0f);
#pragma unroll
    for (int d = 0; d < 16; ++d)
      atomicAdd(&ws_sums[((size_t)(c * VOCAB + ii)) * CDIM + d], zv[d]);

    // commitment: reduce across the wave's 64 lanes, one f64 atomic per wave
#pragma unroll
    for (int off = 32; off; off >>= 1) comm += __shfl_down(comm, off);
    if (lane == 0) atomicAdd(ws_commit, (double)comm);
  }
}

// EMA update + Laplace-smoothed normalization. 128 blocks x 256 threads:
// block = (c, part of 16); each block recomputes its c's nsum (L2-cached),
// then writes a coalesced 1/16 slice of the outputs.
__global__ __launch_bounds__(256) void k_update(
    const float* __restrict__ ema_count, const float* __restrict__ ema_weight,
    const float* __restrict__ ws_counts, const float* __restrict__ ws_sums,
    const double* __restrict__ ws_commit, float* __restrict__ out) {
  const int c = blockIdx.x >> 4;
  const int part = blockIdx.x & 15;
  const int t = threadIdx.x;
  __shared__ float s_red[4];
  __shared__ float s_n;

  float psum = 0.f;
#pragma unroll
  for (int k = 0; k < 4; ++k) {
    const int v = k * 256 + t;
    psum += 0.99f * ema_count[c * VOCAB + v] + 0.01f * ws_counts[c * VOCAB + v];
  }
#pragma unroll
  for (int off = 32; off; off >>= 1) psum += __shfl_down(psum, off);
  if ((t & 63) == 0) s_red[t >> 6] = psum;
  __syncthreads();
  if (t == 0) s_n = (s_red[0] + s_red[1]) + (s_red[2] + s_red[3]);
  __syncthreads();
  const float nsum = s_n;
  const float veps = 0.01024f;  // VOCAB * 1e-5

  // new_count: 64 entries per block
  if (t < 64) {
    const int v = part * 64 + t;
    out[OFF_NCNT + c * VOCAB + v] =
        0.99f * ema_count[c * VOCAB + v] + 0.01f * ws_counts[c * VOCAB + v];
  }

  // new_weight / new_codebooks: 1024 elements per block, coalesced
#pragma unroll
  for (int k = 0; k < 4; ++k) {
    const int i = part * 1024 + k * 256 + t;  // element within codebook c
    const int v = i >> 4;
    const float nc =
        0.99f * ema_count[c * VOCAB + v] + 0.01f * ws_counts[c * VOCAB + v];
    const float cnt = (nc + 1e-5f) / (nsum + veps) * nsum;
    const size_t gi = (size_t)c * VOCAB * CDIM + i;
    const float nw = 0.99f * ema_weight[gi] + 0.01f * ws_sums[gi];
    out[OFF_NWT + gi] = nw;
    out[OFF_NCB + gi] = nw / cnt;
  }
  if (blockIdx.x == 0 && t == 0)
    out[OFF_COMMIT] = (float)(*ws_commit / 1048576.0);
}

extern "C" void kernel_launch(void* const* d_in, const int* in_sizes, int n_in,
                              void* d_out, int out_size, void* d_ws,
                              size_t ws_size, hipStream_t stream) {
  const float* z = (const float*)d_in[0];
  const float* codebooks = (const float*)d_in[1];
  const float* ema_count = (const float*)d_in[2];
  const float* ema_weight = (const float*)d_in[3];
  float* out = (float*)d_out;

  float* wsf = (float*)d_ws;
  float* ws_counts = wsf + WS_COUNTS_OFF;
  float* ws_sums = wsf + WS_SUMS_OFF;
  double* ws_commit = (double*)((char*)d_ws + WS_COMMIT_BYTE_OFF);

  hipMemsetAsync(d_ws, 0, WS_ZERO_BYTES, stream);

  k_assign<<<dim3(256), dim3(512), 0, stream>>>(z, codebooks, out, ws_counts,
                                                ws_sums, ws_commit);
  k_update<<<dim3(128), dim3(256), 0, stream>>>(ema_count, ema_weight,
                                                ws_counts, ws_sums, ws_commit,
                                                out);
}

// Round 7
// 219.516 us; speedup vs baseline: 1.0023x; 1.0023x over previous
//
#include <hip/hip_runtime.h>

// SimVQuantizer: B=8, D=128 (N_CB=8 x CDIM=16), H=W=32 -> 8192 pixels.
// Outputs (FLOAT32, concatenated flat):
//   quantized  [8,128,32,32]  = 1048576   @ 0
//   indices    [8,8,32,32]    =   65536   @ 1048576
//   commitment scalar         =       1   @ 1114112
//   new_codebooks [8,1024,16] =  131072   @ 1114113
//   new_count  [8,1024]       =    8192   @ 1245185
//   new_weight [8,1024,16]    =  131072   @ 1253377

#define NCB   8
#define VOCAB 1024
#define CDIM  16
#define NPIX  8192   // B*H*W
#define HW    1024   // H*W

#define OFF_QUANT  0
#define OFF_IDX    1048576
#define OFF_COMMIT 1114112
#define OFF_NCB    1114113
#define OFF_NCNT   1245185
#define OFF_NWT    1253377

// workspace (bytes): counts f32[8192] @0, sums f32[131072] @32768,
// commit f64 @557056, cand u64[65536] @557064 (all 8-aligned)
#define WS_COUNTS_OFF 0
#define WS_SUMS_OFF   (NCB * VOCAB)
#define WS_COMMIT_BYTE_OFF (size_t)557056
#define WS_CAND_BYTE_OFF   (size_t)557064
#define WS_ZERO_BYTES      (size_t)557064
#define WS_CAND_BYTES      (size_t)(NCB * NPIX * 8)  // 524288

typedef float v2f __attribute__((ext_vector_type(2)));

// numpy pairwise_sum (order-preserving 8-accumulator) for n=16:
// r[j] = a[j] + a[j+8];  res = ((r0+r1)+(r2+r3)) + ((r4+r5)+(r6+r7))
__device__ __forceinline__ float npsum16(const float m[16]) {
#pragma clang fp contract(off)
  float r0 = m[0] + m[8];
  float r1 = m[1] + m[9];
  float r2 = m[2] + m[10];
  float r3 = m[3] + m[11];
  float r4 = m[4] + m[12];
  float r5 = m[5] + m[13];
  float r6 = m[6] + m[14];
  float r7 = m[7] + m[15];
  return ((r0 + r1) + (r2 + r3)) + ((r4 + r5) + (r6 + r7));
}

__device__ __forceinline__ float npsum16sq(const float a[16]) {
#pragma clang fp contract(off)
  float m[16];
#pragma unroll
  for (int d = 0; d < 16; ++d) m[d] = a[d] * a[d];
  return npsum16(m);
}

// 1024 blocks x 512 threads. Block = (q = bx&3 vocab-quarter, c = (bx>>2)&7,
// g = bx>>5 pixel-group of 256). Lane owns 4 pixels; wave w scans 32 staged
// entries for all 256 pixels (one 64B entry-fetch feeds 256 distances).
// Block candidate per pixel merged globally via sortable-key atomicMin_u64:
// key = (monotonic(d2) << 32) | v  -> lexicographic (d2, v) min = np.argmin.
__global__ __launch_bounds__(512, 4) void k_assign(
    const float* __restrict__ z, const float* __restrict__ cb,
    unsigned long long* __restrict__ ws_cand) {
  __shared__ float4 s_cb4[256 * 4];  // 16KB: this block's 256 entries
  __shared__ float s_c2[256];        // 1KB
  __shared__ float s_best[8 * 256];  // 8KB
  __shared__ int s_bi[8 * 256];      // 8KB

  const int q = blockIdx.x & 3;
  const int c = (blockIdx.x >> 2) & 7;
  const int g = blockIdx.x >> 5;
  const int t = threadIdx.x;
  const int lane = t & 63;
  const int w = t >> 6;

  const float4* cb4 =
      reinterpret_cast<const float4*>(cb) + ((size_t)c * VOCAB + q * 256) * 4;

  // stage quarter codebook: 2 float4 per thread, coalesced
  s_cb4[t] = cb4[t];
  s_cb4[512 + t] = cb4[512 + t];

  // ||cb||^2 for the 256 entries (np.sum(cb*cb,-1), pairwise 8-acc order)
  if (t < 256) {
    const float* ep = reinterpret_cast<const float*>(cb4 + (size_t)t * 4);
    float e[16];
#pragma unroll
    for (int d = 0; d < 16; ++d) e[d] = ep[d];
    s_c2[t] = npsum16sq(e);
  }

  // z for this lane's 4 pixels (coalesced per d); block batch is constant
  const int bb = g >> 2;
  v2f Z[4][8];
  float z2[4];
#pragma unroll
  for (int sub = 0; sub < 4; ++sub) {
    const int n = g * 256 + sub * 64 + lane;
    const int hw = n & 1023;
    const float* zbase = z + ((size_t)(bb * 128 + c * 16)) * HW + hw;
    float zv[16];
#pragma unroll
    for (int d = 0; d < 16; ++d) zv[d] = zbase[(size_t)d * HW];
    z2[sub] = npsum16sq(zv);
#pragma unroll
    for (int j = 0; j < 8; ++j) Z[sub][j] = (v2f){zv[2 * j], zv[2 * j + 1]};
  }
  __syncthreads();

  float best[4] = {INFINITY, INFINITY, INFINITY, INFINITY};
  int bi[4] = {0, 0, 0, 0};

  const float4* sl4 = s_cb4 + w * 32 * 4;  // wave's 32 entries (wave-uniform)
  const int vbase = q * 256 + w * 32;
#pragma unroll 2
  for (int vo = 0; vo < 32; ++vo) {
    const float4 q0 = sl4[vo * 4 + 0];
    const float4 q1 = sl4[vo * 4 + 1];
    const float4 q2 = sl4[vo * 4 + 2];
    const float4 q3 = sl4[vo * 4 + 3];
    const float cc2 = s_c2[w * 32 + vo];
    const int v = vbase + vo;
#pragma unroll
    for (int sub = 0; sub < 4; ++sub) {
      float d2;
      {
#pragma clang fp contract(off)
        // exact numpy-einsum order via packed fp32 (bit-identical/elem):
        // l_j = (m_j+m_{j+4}) + (m_{j+8}+m_{j+12}); res = (l0+l1)+(l2+l3)
        const v2f M0 = Z[sub][0] * (v2f){q0.x, q0.y};
        const v2f M1 = Z[sub][1] * (v2f){q0.z, q0.w};
        const v2f M2 = Z[sub][2] * (v2f){q1.x, q1.y};
        const v2f M3 = Z[sub][3] * (v2f){q1.z, q1.w};
        const v2f M4 = Z[sub][4] * (v2f){q2.x, q2.y};
        const v2f M5 = Z[sub][5] * (v2f){q2.z, q2.w};
        const v2f M6 = Z[sub][6] * (v2f){q3.x, q3.y};
        const v2f M7 = Z[sub][7] * (v2f){q3.z, q3.w};
        const v2f A = M0 + M2;
        const v2f Bp = M1 + M3;
        const v2f C = M4 + M6;
        const v2f D = M5 + M7;
        const v2f E = A + C;   // (l0, l1)
        const v2f F = Bp + D;  // (l2, l3)
        const float dot = (E.x + E.y) + (F.x + F.y);
        d2 = (z2[sub] - 2.0f * dot) + cc2;  // np: (z2-2*einsum)+c2
      }
      const bool lt = d2 < best[sub];  // strict <, ascending v within wave
      best[sub] = lt ? d2 : best[sub];
      bi[sub] = lt ? v : bi[sub];
    }
  }
#pragma unroll
  for (int sub = 0; sub < 4; ++sub) {
    s_best[w * 256 + sub * 64 + lane] = best[sub];
    s_bi[w * 256 + sub * 64 + lane] = bi[sub];
  }
  __syncthreads();

  // waves 0..3: wave w combines sub w across the 8 waves (index tie-break),
  // then merges the block candidate globally via atomicMin on (key | v).
  if (w < 4) {
    const int sub = w;
    float bbst = s_best[sub * 64 + lane];
    int ii = s_bi[sub * 64 + lane];
#pragma unroll
    for (int s = 1; s < 8; ++s) {
      const float ob = s_best[s * 256 + sub * 64 + lane];
      const int oi = s_bi[s * 256 + sub * 64 + lane];
      const bool take = (ob < bbst) || (ob == bbst && oi < ii);
      bbst = take ? ob : bbst;
      ii = take ? oi : ii;
    }
    const int n = g * 256 + sub * 64 + lane;
    const unsigned int fb = __float_as_uint(bbst);
    const unsigned int key = fb ^ (((unsigned int)((int)fb >> 31)) | 0x80000000u);
    const unsigned long long pack =
        ((unsigned long long)key << 32) | (unsigned int)ii;
    atomicMin(&ws_cand[(size_t)c * NPIX + n], pack);
  }
}

// Epilogue: 128 blocks x 512 threads; thread = one (pixel, codebook) task.
// Runs after all k_assign blocks (stream order) -> cand is final.
__global__ __launch_bounds__(512) void k_final(
    const float* __restrict__ z, const float* __restrict__ cb,
    const unsigned long long* __restrict__ ws_cand, float* __restrict__ out,
    float* __restrict__ ws_counts, float* __restrict__ ws_sums,
    double* __restrict__ ws_commit) {
  const int t = threadIdx.x;
  const int c = blockIdx.x >> 4;
  const int n = ((blockIdx.x & 15) << 9) | t;  // 512-aligned -> same batch
  const int b = n >> 10;
  const int hw = n & 1023;

  const int bi = (int)(ws_cand[(size_t)c * NPIX + n] & 0xFFFFFFFFull);

  const float* zbase = z + ((size_t)(b * 128 + c * 16)) * HW + hw;
  float zv[16];
#pragma unroll
  for (int d = 0; d < 16; ++d) zv[d] = zbase[(size_t)d * HW];

  // winning entry: per-lane gather, 4x float4 (cb is 512KB, L2-hot)
  const float4* qe4 = reinterpret_cast<const float4*>(
      cb + ((size_t)c * VOCAB + bi) * CDIM);
  float qe[16];
  {
    const float4 q0 = qe4[0], q1 = qe4[1], q2 = qe4[2], q3 = qe4[3];
    qe[0] = q0.x; qe[1] = q0.y; qe[2] = q0.z; qe[3] = q0.w;
    qe[4] = q1.x; qe[5] = q1.y; qe[6] = q1.z; qe[7] = q1.w;
    qe[8] = q2.x; qe[9] = q2.y; qe[10] = q2.z; qe[11] = q2.w;
    qe[12] = q3.x; qe[13] = q3.y; qe[14] = q3.z; qe[15] = q3.w;
  }

  float comm = 0.f;
#pragma unroll
  for (int d = 0; d < 16; ++d) {
    float diff, qst;
    {
#pragma clang fp contract(off)
      diff = zv[d] - qe[d];
      qst = zv[d] + (qe[d] - zv[d]);  // zq_st = zp + (zq - zp), as np computes
    }
    comm += diff * diff;
    out[OFF_QUANT + ((size_t)(b * 128 + c * 16 + d)) * HW + hw] = qst;
  }
  out[OFF_IDX + ((size_t)(b * NCB + c)) * HW + hw] = (float)bi;

  atomicAdd(&ws_counts[c * VOCAB + bi], 1.0f);
#pragma unroll
  for (int d = 0; d < 16; ++d)
    atomicAdd(&ws_sums[((size_t)(c * VOCAB + bi)) * CDIM + d], zv[d]);

  // commitment: per-wave reduce, one f64 atomic per wave
#pragma unroll
  for (int off = 32; off; off >>= 1) comm += __shfl_down(comm, off);
  if ((t & 63) == 0) atomicAdd(ws_commit, (double)comm);
}

// EMA update + Laplace-smoothed normalization. 128 blocks x 256 threads:
// block = (c, part of 16); each block recomputes its c's nsum (L2-cached),
// then writes a coalesced 1/16 slice of the outputs.
__global__ __launch_bounds__(256) void k_update(
    const float* __restrict__ ema_count, const float* __restrict__ ema_weight,
    const float* __restrict__ ws_counts, const float* __restrict__ ws_sums,
    const double* __restrict__ ws_commit, float* __restrict__ out) {
  const int c = blockIdx.x >> 4;
  const int part = blockIdx.x & 15;
  const int t = threadIdx.x;
  __shared__ float s_red[4];
  __shared__ float s_n;

  float psum = 0.f;
#pragma unroll
  for (int k = 0; k < 4; ++k) {
    const int v = k * 256 + t;
    psum += 0.99f * ema_count[c * VOCAB + v] + 0.01f * ws_counts[c * VOCAB + v];
  }
#pragma unroll
  for (int off = 32; off; off >>= 1) psum += __shfl_down(psum, off);
  if ((t & 63) == 0) s_red[t >> 6] = psum;
  __syncthreads();
  if (t == 0) s_n = (s_red[0] + s_red[1]) + (s_red[2] + s_red[3]);
  __syncthreads();
  const float nsum = s_n;
  const float veps = 0.01024f;  // VOCAB * 1e-5

  // new_count: 64 entries per block
  if (t < 64) {
    const int v = part * 64 + t;
    out[OFF_NCNT + c * VOCAB + v] =
        0.99f * ema_count[c * VOCAB + v] + 0.01f * ws_counts[c * VOCAB + v];
  }

  // new_weight / new_codebooks: 1024 elements per block, coalesced
#pragma unroll
  for (int k = 0; k < 4; ++k) {
    const int i = part * 1024 + k * 256 + t;  // element within codebook c
    const int v = i >> 4;
    const float nc =
        0.99f * ema_count[c * VOCAB + v] + 0.01f * ws_counts[c * VOCAB + v];
    const float cnt = (nc + 1e-5f) / (nsum + veps) * nsum;
    const size_t gi = (size_t)c * VOCAB * CDIM + i;
    const float nw = 0.99f * ema_weight[gi] + 0.01f * ws_sums[gi];
    out[OFF_NWT + gi] = nw;
    out[OFF_NCB + gi] = nw / cnt;
  }
  if (blockIdx.x == 0 && t == 0)
    out[OFF_COMMIT] = (float)(*ws_commit / 1048576.0);
}

extern "C" void kernel_launch(void* const* d_in, const int* in_sizes, int n_in,
                              void* d_out, int out_size, void* d_ws,
                              size_t ws_size, hipStream_t stream) {
  const float* z = (const float*)d_in[0];
  const float* codebooks = (const float*)d_in[1];
  const float* ema_count = (const float*)d_in[2];
  const float* ema_weight = (const float*)d_in[3];
  float* out = (float*)d_out;

  float* wsf = (float*)d_ws;
  float* ws_counts = wsf + WS_COUNTS_OFF;
  float* ws_sums = wsf + WS_SUMS_OFF;
  double* ws_commit = (double*)((char*)d_ws + WS_COMMIT_BYTE_OFF);
  unsigned long long* ws_cand =
      (unsigned long long*)((char*)d_ws + WS_CAND_BYTE_OFF);

  hipMemsetAsync(d_ws, 0, WS_ZERO_BYTES, stream);
  hipMemsetAsync((void*)ws_cand, 0xFF, WS_CAND_BYTES, stream);

  k_assign<<<dim3(1024), dim3(512), 0, stream>>>(z, codebooks, ws_cand);
  k_final<<<dim3(128), dim3(512), 0, stream>>>(z, codebooks, ws_cand, out,
                                               ws_counts, ws_sums, ws_commit);
  k_update<<<dim3(128), dim3(256), 0, stream>>>(ema_count, ema_weight,
                                                ws_counts, ws_sums, ws_commit,
                                                out);
}